// Round 4
// baseline (222.917 us; speedup 1.0000x reference)
//
#include <hip/hip_runtime.h>
#include <math.h>

#define LOG_EPS   (-18.420680743952367f)   // ln(1e-8)
#define LOG_INV_K (-2.772588722239781f)    // ln(1/16)

// ---------------------------------------------------------------------------
// Kernel A: 32 blocks -> W_eff = W_slot @ W_fusion, b_eff
// (sinkhorn G lives in kB block 0 so it overlaps kB's row blocks)
// ---------------------------------------------------------------------------
__global__ __launch_bounds__(256) void kA(const float* __restrict__ W_fusion,
                   const float* __restrict__ b_fusion,
                   const float* __restrict__ W_slot,   const float* __restrict__ b_slot,
                   float* __restrict__ W_eff, float* __restrict__ b_eff) {
    int t = threadIdx.x;
    int idx = blockIdx.x * 256 + t;          // 0..8191
    int k = idx >> 9, j = idx & 511;
    const float* ws = W_slot + k * 256;
    // 4 accumulators: break the 256-deep dependent FMA chain
    float s0 = 0.f, s1 = 0.f, s2 = 0.f, s3 = 0.f;
    for (int d = 0; d < 256; d += 4) {
        s0 += ws[d + 0] * W_fusion[(d + 0) * 512 + j];
        s1 += ws[d + 1] * W_fusion[(d + 1) * 512 + j];
        s2 += ws[d + 2] * W_fusion[(d + 2) * 512 + j];
        s3 += ws[d + 3] * W_fusion[(d + 3) * 512 + j];
    }
    W_eff[idx] = (s0 + s1) + (s2 + s3);
    if (idx < 16) {
        float bb = b_slot[idx];
        for (int d = 0; d < 256; ++d) bb += W_slot[idx * 256 + d] * b_fusion[d];
        b_eff[idx] = bb;
    }
}

// ---------------------------------------------------------------------------
// Kernel B: block 0       -> G softmax+sinkhorn+zero-diag + Frobenius reg
//           blocks 1..2048 -> S = softmax(concat(desc,nv) @ W_eff^T + b_eff)
// G is block 0 so it's dispatched FIRST and overlaps the 8 row-block rounds
// (as block 2048 it was dispatched last -> pure serial tail, ~+4 us).
// ---------------------------------------------------------------------------
__global__ __launch_bounds__(256) void kB(const float* __restrict__ desc, const float* __restrict__ nv,
                   const float* __restrict__ W_eff, const float* __restrict__ b_eff,
                   const float* __restrict__ G_param,
                   float* __restrict__ S, float* __restrict__ G_out,
                   float* __restrict__ out_reg) {
    __shared__ float M[2048];
    __shared__ float red[256];
    __shared__ float inv_nrm[8];
    __shared__ float hsq[8];
    __shared__ float trace_s;
    int t = threadIdx.x;

    if (blockIdx.x == 0) {
        // ---- G block: softmax rows -> sinkhorn -> zero diag -> Frobenius reg ----
        if (t < 128) {
            int base = t * 16;
            float v[16]; float mx = -1e30f;
            #pragma unroll
            for (int l = 0; l < 16; ++l) { v[l] = G_param[base + l]; mx = fmaxf(mx, v[l]); }
            float s = 0.f;
            #pragma unroll
            for (int l = 0; l < 16; ++l) { v[l] = expf(v[l] - mx); s += v[l]; }
            float r = 1.f / s;
            #pragma unroll
            for (int l = 0; l < 16; ++l) M[base + l] = fmaxf(v[l] * r, 1e-6f);
        }
        __syncthreads();
        for (int it = 0; it < 10; ++it) {
            if (t < 128) {
                float s = 0.f;
                #pragma unroll
                for (int l = 0; l < 16; ++l) s += M[t * 16 + l];
                float r = 1.f / (s + 1e-6f);
                #pragma unroll
                for (int l = 0; l < 16; ++l) M[t * 16 + l] *= r;
            }
            __syncthreads();
            if (t < 128) {
                int h = t >> 4, l = t & 15, base = h * 256 + l;
                float s = 0.f;
                #pragma unroll
                for (int k = 0; k < 16; ++k) s += M[base + k * 16];
                float r = 1.f / (s + 1e-6f);
                #pragma unroll
                for (int k = 0; k < 16; ++k) M[base + k * 16] *= r;
            }
            __syncthreads();
        }
        if (t < 128) { int h = t >> 4, k = t & 15; M[h * 256 + k * 16 + k] = 0.f; }
        __syncthreads();
        for (int i = t; i < 2048; i += 256) G_out[i] = M[i];

        if (t < 128) {
            float s = 0.f;
            #pragma unroll
            for (int l = 0; l < 16; ++l) { float x = M[t * 16 + l]; s += x * x; }
            red[t] = s;
        }
        __syncthreads();
        if (t < 8) {
            float s = 0.f;
            for (int k = 0; k < 16; ++k) s += red[t * 16 + k];
            float inv = 1.f / fmaxf(sqrtf(s), 1e-8f);
            inv_nrm[t] = inv;
            hsq[t] = s * inv * inv;
        }
        __syncthreads();
        if (t == 0) {
            float tr = 0.f;
            for (int h = 0; h < 8; ++h) tr += hsq[h];
            trace_s = tr;
        }
        __syncthreads();
        float w = 0.f;
        #pragma unroll
        for (int h = 0; h < 8; ++h) w += M[h * 256 + t] * inv_nrm[h];
        red[t] = w * w;
        __syncthreads();
        for (int off = 128; off; off >>= 1) {
            if (t < off) red[t] += red[t + off];
            __syncthreads();
        }
        if (t == 0) out_reg[0] = 0.02f * (red[0] - trace_s) / 56.f;
        return;
    }

    // ---- row blocks: wave per row ----
    int row  = (blockIdx.x - 1) * 4 + (t >> 6);
    int lane = t & 63;
    int k = lane & 15, q = lane >> 4;
    const float* x = (q < 2) ? (desc + (size_t)row * 256 + q * 128)
                             : (nv   + (size_t)row * 256 + (q - 2) * 128);
    const float4* x4 = (const float4*)x;
    const float4* w4 = (const float4*)(W_eff + k * 512 + q * 128);
    float acc = 0.f;
    #pragma unroll
    for (int i = 0; i < 32; ++i) {
        float4 a = x4[i], b = w4[i];
        acc += a.x * b.x + a.y * b.y + a.z * b.z + a.w * b.w;
    }
    acc += __shfl_xor(acc, 16);
    acc += __shfl_xor(acc, 32);
    float logit = acc + b_eff[k];
    float mx = logit;
    #pragma unroll
    for (int off = 8; off; off >>= 1) mx = fmaxf(mx, __shfl_xor(mx, off));
    float e = __expf(logit - mx);
    float s = e;
    #pragma unroll
    for (int off = 8; off; off >>= 1) s += __shfl_xor(s, off);
    if (q == 0) S[(size_t)row * 16 + k] = e / s;
}

// ---------------------------------------------------------------------------
// Kernel C: blocks 0..1023  -> affinity: blk>>2 = (b,h), blk&3 = 64-row slice
//           blocks 1024..1055 -> per-batch regularizers, atomicAdd into out_reg
//
// x = 2*(S G)·S  in [0,2]  (S rows are softmax outputs; sinkhorn G entries <=1)
// -> logsumexp with shift 0: no max pass.  exp computed ONCE per element.
// Store layout: thread t -> columns 4*(t&63)..+3 of rows r = (t>>6) mod 4
// (adjacent lanes adjacent addresses -> wave writes 1 KB contiguous).
// S staged TRANSPOSED in LDS (stride 260) so column reads are the standard
// lanes-read-consecutive-float4 conflict-free pattern.
// ---------------------------------------------------------------------------
__global__ __launch_bounds__(256) void kC(const float* __restrict__ S,
                                          const float* __restrict__ G,
                                          float* __restrict__ bias,
                                          float* __restrict__ Q,
                                          float* __restrict__ out_reg) {
    __shared__ float smem[5696];    // 22.8 KB, overlaid per branch
    int t = threadIdx.x;
    int blk = blockIdx.x;

    if (blk >= 1024) {
        // ---- regularizer block for batch b ----
        float* Su  = smem;          // [256][16]
        float* red = smem + 4096;   // [256]
        float* ps  = smem + 4352;   // [16]
        int b = blk - 1024;
        for (int i = t; i < 4096; i += 256) Su[i] = S[(size_t)b * 4096 + i];
        __syncthreads();
        int k = t >> 4, l = t & 15;
        float s = 0.f;
        for (int n = 0; n < 256; ++n) s += Su[n * 16 + k] * Su[n * 16 + l];
        s *= (1.f / 256.f);
        red[t] = (k == l) ? 0.f : s * s;
        __syncthreads();
        for (int off = 128; off; off >>= 1) {
            if (t < off) red[t] += red[t + off];
            __syncthreads();
        }
        if (t < 16) {
            float u = 0.f;
            for (int n = 0; n < 256; ++n) u += Su[n * 16 + t];
            ps[t] = u * (1.f / 256.f);
        }
        __syncthreads();
        if (t == 0) {
            float su = 0.f;
            for (int kk = 0; kk < 16; ++kk) su += ps[kk];
            float kl = 0.f;
            for (int kk = 0; kk < 16; ++kk) {
                float uc = fmaxf(ps[kk] / (su + 1e-8f), 1e-8f);
                kl += uc * (logf(uc) - LOG_INV_K);
            }
            float val = 0.1f * red[0] / 8192.f + 0.1f * kl / 32.f;
            atomicAdd(out_reg, val);
        }
        return;
    }

    // ---- affinity ----
    float* St = smem;               // [16][260]  S_b transposed, padded
    float* Rl = smem + 4160;        // [64][20]   2*(S G) rows for this slice
    float* Gl = smem + 5440;        // [16][16]
    int bh = blk >> 2, qq = blk & 3;
    int b = bh >> 3, h = bh & 7;
    int n0 = qq * 64;

    // stage: S_b transposed + G_h
    {
        const float4* Sg = (const float4*)(S + (size_t)b * 4096);
        for (int i = t; i < 1024; i += 256) {
            int row = i >> 2, q = i & 3;
            float4 v = Sg[i];
            St[(4 * q + 0) * 260 + row] = v.x;
            St[(4 * q + 1) * 260 + row] = v.y;
            St[(4 * q + 2) * 260 + row] = v.z;
            St[(4 * q + 3) * 260 + row] = v.w;
        }
        Gl[t] = G[h * 256 + t];
    }
    __syncthreads();

    // R[r][l] = 2 * sum_k S[n0+r][k] * G_h[k][l]; thread t -> r=t>>2, l4=(t&3)*4
    {
        int r = t >> 2, l4 = (t & 3) * 4;
        const float4* mp = (const float4*)(S + (size_t)b * 4096 + (size_t)(n0 + r) * 16);
        float4 s0 = mp[0], s1 = mp[1], s2 = mp[2], s3 = mp[3];
        float sr[16] = { s0.x,s0.y,s0.z,s0.w, s1.x,s1.y,s1.z,s1.w,
                         s2.x,s2.y,s2.z,s2.w, s3.x,s3.y,s3.z,s3.w };
        float a0 = 0.f, a1 = 0.f, a2 = 0.f, a3 = 0.f;
        #pragma unroll
        for (int k = 0; k < 16; ++k) {
            float4 g = *(const float4*)(Gl + k * 16 + l4);
            a0 += sr[k] * g.x; a1 += sr[k] * g.y;
            a2 += sr[k] * g.z; a3 += sr[k] * g.w;
        }
        *(float4*)(Rl + r * 20 + l4) = make_float4(2.f*a0, 2.f*a1, 2.f*a2, 2.f*a3);
    }
    __syncthreads();

    // main: cg = t&63 -> columns 4cg..4cg+3; wave rs = t>>6 -> rows rs, rs+4, ...
    int cg = t & 63, rs = t >> 6;
    float sr[4][16];                       // S rows of my 4 columns
    #pragma unroll
    for (int k = 0; k < 16; ++k) {
        float4 v = *(const float4*)(St + k * 260 + 4 * cg);   // conflict-free b128
        sr[0][k] = v.x; sr[1][k] = v.y; sr[2][k] = v.z; sr[3][k] = v.w;
    }
    size_t obase = (size_t)bh * 65536 + (size_t)n0 * 256 + 4 * cg;
    for (int r = rs; r < 64; r += 4) {
        const float4* rp = (const float4*)(Rl + r * 20);      // wave-uniform bcast
        float4 r0 = rp[0], r1 = rp[1], r2 = rp[2], r3 = rp[3];
        float rv[16] = { r0.x,r0.y,r0.z,r0.w, r1.x,r1.y,r1.z,r1.w,
                         r2.x,r2.y,r2.z,r2.w, r3.x,r3.y,r3.z,r3.w };
        float x[4], e[4];
        #pragma unroll
        for (int j = 0; j < 4; ++j) {
            float a = 0.f;
            #pragma unroll
            for (int l = 0; l < 16; ++l) a += rv[l] * sr[j][l];
            x[j] = a;
            e[j] = __expf(a);
        }
        float ls = (e[0] + e[1]) + (e[2] + e[3]);
        #pragma unroll
        for (int off = 1; off < 64; off <<= 1) ls += __shfl_xor(ls, off);
        float lnL = __logf(ls);
        float rc = 1.f / ls;
        size_t ro = obase + (size_t)r * 256;
        *(float4*)(Q + ro)    = make_float4(e[0]*rc, e[1]*rc, e[2]*rc, e[3]*rc);
        *(float4*)(bias + ro) = make_float4(fmaxf(x[0]-lnL, LOG_EPS),
                                            fmaxf(x[1]-lnL, LOG_EPS),
                                            fmaxf(x[2]-lnL, LOG_EPS),
                                            fmaxf(x[3]-lnL, LOG_EPS));
    }
}

// ---------------------------------------------------------------------------
extern "C" void kernel_launch(void* const* d_in, const int* in_sizes, int n_in,
                              void* d_out, int out_size, void* d_ws, size_t ws_size,
                              hipStream_t stream) {
    const float* desc     = (const float*)d_in[0];
    const float* nv       = (const float*)d_in[1];
    const float* W_fusion = (const float*)d_in[2];
    const float* b_fusion = (const float*)d_in[3];
    const float* W_slot   = (const float*)d_in[4];
    const float* b_slot   = (const float*)d_in[5];
    const float* G_param  = (const float*)d_in[6];

    float* out = (float*)d_out;
    float* out_bias = out;
    float* out_Q    = out + 16777216;
    float* out_reg  = out + 33554432;

    float* ws    = (float*)d_ws;
    float* W_eff = ws;           // 8192
    float* b_eff = ws + 8192;    // 16
    float* G_out = ws + 8208;    // 2048
    float* S     = ws + 10256;   // 131072

    kA<<<32, 256, 0, stream>>>(W_fusion, b_fusion, W_slot, b_slot, W_eff, b_eff);
    kB<<<2049, 256, 0, stream>>>(desc, nv, W_eff, b_eff, G_param, S, G_out, out_reg);
    kC<<<1056, 256, 0, stream>>>(S, G_out, out_bias, out_Q, out_reg);
}

// Round 5
// 218.562 us; speedup vs baseline: 1.0199x; 1.0199x over previous
//
#include <hip/hip_runtime.h>
#include <math.h>

#define LOG_EPS   (-18.420680743952367f)   // ln(1e-8)
#define LOG_INV_K (-2.772588722239781f)    // ln(1/16)

// ---------------------------------------------------------------------------
// Kernel A: 32 blocks -> W_eff = W_slot @ W_fusion, b_eff
// ---------------------------------------------------------------------------
__global__ __launch_bounds__(256) void kA(const float* __restrict__ W_fusion,
                   const float* __restrict__ b_fusion,
                   const float* __restrict__ W_slot,   const float* __restrict__ b_slot,
                   float* __restrict__ W_eff, float* __restrict__ b_eff) {
    int t = threadIdx.x;
    int idx = blockIdx.x * 256 + t;          // 0..8191
    int k = idx >> 9, j = idx & 511;
    const float* ws = W_slot + k * 256;
    float s0 = 0.f, s1 = 0.f, s2 = 0.f, s3 = 0.f;
    for (int d = 0; d < 256; d += 4) {
        s0 += ws[d + 0] * W_fusion[(d + 0) * 512 + j];
        s1 += ws[d + 1] * W_fusion[(d + 1) * 512 + j];
        s2 += ws[d + 2] * W_fusion[(d + 2) * 512 + j];
        s3 += ws[d + 3] * W_fusion[(d + 3) * 512 + j];
    }
    W_eff[idx] = (s0 + s1) + (s2 + s3);
    if (idx < 16) {
        float bb = b_slot[idx];
        for (int d = 0; d < 256; ++d) bb += W_slot[idx * 256 + d] * b_fusion[d];
        b_eff[idx] = bb;
    }
}

// ---------------------------------------------------------------------------
// Kernel B: block 0       -> G sinkhorn, single wave, REGISTER-RESIDENT:
//                            lane = 8*h + sub owns rows {2sub, 2sub+1} of head h.
//                            row-norm in-register; col-norm via shfl_xor(1,2,4)
//                            inside the 8-lane head group. ZERO barriers / LDS
//                            (the old 128-thread+LDS version ran ~21 syncthreads
//                            and was the long pole of this dispatch).
//           blocks 1..2048 -> S = softmax(concat(desc,nv) @ W_eff^T + b_eff)
// ---------------------------------------------------------------------------
__global__ __launch_bounds__(256) void kB(const float* __restrict__ desc, const float* __restrict__ nv,
                   const float* __restrict__ W_eff, const float* __restrict__ b_eff,
                   const float* __restrict__ G_param,
                   float* __restrict__ S, float* __restrict__ G_out,
                   float* __restrict__ out_reg) {
    int t = threadIdx.x;

    if (blockIdx.x == 0) {
        if (t >= 64) return;                 // single wave; no barriers below
        int h = t >> 3, sub = t & 7;
        int r0 = 2 * sub, r1 = r0 + 1;
        const float* gp = G_param + h * 256;
        float a0[16], a1[16];
        #pragma unroll
        for (int l = 0; l < 16; l += 4) {
            float4 v = *(const float4*)(gp + r0 * 16 + l);
            a0[l] = v.x; a0[l+1] = v.y; a0[l+2] = v.z; a0[l+3] = v.w;
            float4 w = *(const float4*)(gp + r1 * 16 + l);
            a1[l] = w.x; a1[l+1] = w.y; a1[l+2] = w.z; a1[l+3] = w.w;
        }
        // per-row softmax + clamp to SINK_EPS
        {
            float m0 = -1e30f, m1 = -1e30f;
            #pragma unroll
            for (int l = 0; l < 16; ++l) { m0 = fmaxf(m0, a0[l]); m1 = fmaxf(m1, a1[l]); }
            float s0 = 0.f, s1 = 0.f;
            #pragma unroll
            for (int l = 0; l < 16; ++l) { a0[l] = expf(a0[l] - m0); s0 += a0[l];
                                           a1[l] = expf(a1[l] - m1); s1 += a1[l]; }
            float i0 = 1.f / s0, i1 = 1.f / s1;
            #pragma unroll
            for (int l = 0; l < 16; ++l) { a0[l] = fmaxf(a0[l] * i0, 1e-6f);
                                           a1[l] = fmaxf(a1[l] * i1, 1e-6f); }
        }
        // 10 sinkhorn iterations, barrier-free
        for (int it = 0; it < 10; ++it) {
            float s0 = 0.f, s1 = 0.f;
            #pragma unroll
            for (int l = 0; l < 16; ++l) { s0 += a0[l]; s1 += a1[l]; }
            float i0 = 1.f / (s0 + 1e-6f), i1 = 1.f / (s1 + 1e-6f);
            float c[16];
            #pragma unroll
            for (int l = 0; l < 16; ++l) {
                a0[l] *= i0; a1[l] *= i1;
                c[l] = a0[l] + a1[l];
            }
            #pragma unroll
            for (int l = 0; l < 16; ++l) {
                c[l] += __shfl_xor(c[l], 1);
                c[l] += __shfl_xor(c[l], 2);
                c[l] += __shfl_xor(c[l], 4);     // col sums over the head's 16 rows
                float ic = 1.f / (c[l] + 1e-6f);
                a0[l] *= ic; a1[l] *= ic;
            }
        }
        // zero diagonal (predicated; keeps arrays in registers)
        #pragma unroll
        for (int l = 0; l < 16; ++l) {
            a0[l] = (l == r0) ? 0.f : a0[l];
            a1[l] = (l == r1) ? 0.f : a1[l];
        }
        // store G
        float* go = G_out + h * 256;
        #pragma unroll
        for (int l = 0; l < 16; l += 4) {
            *(float4*)(go + r0 * 16 + l) = make_float4(a0[l], a0[l+1], a0[l+2], a0[l+3]);
            *(float4*)(go + r1 * 16 + l) = make_float4(a1[l], a1[l+1], a1[l+2], a1[l+3]);
        }
        // Frobenius diversity reg, register+shuffle
        float ss = 0.f;
        #pragma unroll
        for (int l = 0; l < 16; ++l) ss += a0[l] * a0[l] + a1[l] * a1[l];
        ss += __shfl_xor(ss, 1); ss += __shfl_xor(ss, 2); ss += __shfl_xor(ss, 4);
        float inv = 1.f / fmaxf(sqrtf(ss), 1e-8f);
        float hsq = ss * inv * inv;          // V_h . V_h
        float q = 0.f;
        #pragma unroll
        for (int l = 0; l < 16; ++l) {
            float w0 = a0[l] * inv, w1 = a1[l] * inv;
            w0 += __shfl_xor(w0, 8); w0 += __shfl_xor(w0, 16); w0 += __shfl_xor(w0, 32);
            w1 += __shfl_xor(w1, 8); w1 += __shfl_xor(w1, 16); w1 += __shfl_xor(w1, 32);
            q += w0 * w0 + w1 * w1;          // w_j = sum_h V_h[j]
        }
        q += __shfl_xor(q, 1); q += __shfl_xor(q, 2); q += __shfl_xor(q, 4);  // Gram.sum()
        float tr = hsq;
        tr += __shfl_xor(tr, 8); tr += __shfl_xor(tr, 16); tr += __shfl_xor(tr, 32);
        if (t == 0) out_reg[0] = 0.02f * (q - tr) / 56.f;
        return;
    }

    // ---- row blocks: wave per row ----
    int row  = (blockIdx.x - 1) * 4 + (t >> 6);
    int lane = t & 63;
    int k = lane & 15, q = lane >> 4;
    const float* x = (q < 2) ? (desc + (size_t)row * 256 + q * 128)
                             : (nv   + (size_t)row * 256 + (q - 2) * 128);
    const float4* x4 = (const float4*)x;
    const float4* w4 = (const float4*)(W_eff + k * 512 + q * 128);
    float acc = 0.f;
    #pragma unroll
    for (int i = 0; i < 32; ++i) {
        float4 a = x4[i], b = w4[i];
        acc += a.x * b.x + a.y * b.y + a.z * b.z + a.w * b.w;
    }
    acc += __shfl_xor(acc, 16);
    acc += __shfl_xor(acc, 32);
    float logit = acc + b_eff[k];
    float mx = logit;
    #pragma unroll
    for (int off = 8; off; off >>= 1) mx = fmaxf(mx, __shfl_xor(mx, off));
    float e = __expf(logit - mx);
    float s = e;
    #pragma unroll
    for (int off = 8; off; off >>= 1) s += __shfl_xor(s, off);
    if (q == 0) S[(size_t)row * 16 + k] = e / s;
}

// ---------------------------------------------------------------------------
// Kernel C: blocks 0..1023  -> affinity: blk>>2 = (b,h), blk&3 = 64-row slice
//           blocks 1024..1055 -> per-batch regularizers, atomicAdd into out_reg
// ---------------------------------------------------------------------------
__global__ __launch_bounds__(256) void kC(const float* __restrict__ S,
                                          const float* __restrict__ G,
                                          float* __restrict__ bias,
                                          float* __restrict__ Q,
                                          float* __restrict__ out_reg) {
    __shared__ float smem[5696];    // 22.8 KB, overlaid per branch
    int t = threadIdx.x;
    int blk = blockIdx.x;

    if (blk >= 1024) {
        // ---- regularizer block for batch b ----
        float* Su  = smem;          // [256][16]
        float* red = smem + 4096;   // [256]
        float* ps  = smem + 4352;   // [16]
        int b = blk - 1024;
        for (int i = t; i < 4096; i += 256) Su[i] = S[(size_t)b * 4096 + i];
        __syncthreads();
        int k = t >> 4, l = t & 15;
        float s = 0.f;
        for (int n = 0; n < 256; ++n) s += Su[n * 16 + k] * Su[n * 16 + l];
        s *= (1.f / 256.f);
        red[t] = (k == l) ? 0.f : s * s;
        __syncthreads();
        for (int off = 128; off; off >>= 1) {
            if (t < off) red[t] += red[t + off];
            __syncthreads();
        }
        if (t < 16) {
            float u = 0.f;
            for (int n = 0; n < 256; ++n) u += Su[n * 16 + t];
            ps[t] = u * (1.f / 256.f);
        }
        __syncthreads();
        if (t == 0) {
            float su = 0.f;
            for (int kk = 0; kk < 16; ++kk) su += ps[kk];
            float kl = 0.f;
            for (int kk = 0; kk < 16; ++kk) {
                float uc = fmaxf(ps[kk] / (su + 1e-8f), 1e-8f);
                kl += uc * (logf(uc) - LOG_INV_K);
            }
            float val = 0.1f * red[0] / 8192.f + 0.1f * kl / 32.f;
            atomicAdd(out_reg, val);
        }
        return;
    }

    // ---- affinity ----
    float* St = smem;               // [16][260]  S_b transposed, padded
    float* Rl = smem + 4160;        // [64][20]   2*(S G) rows for this slice
    float* Gl = smem + 5440;        // [16][16]
    int bh = blk >> 2, qq = blk & 3;
    int b = bh >> 3, h = bh & 7;
    int n0 = qq * 64;

    // stage: S_b transposed + G_h
    {
        const float4* Sg = (const float4*)(S + (size_t)b * 4096);
        for (int i = t; i < 1024; i += 256) {
            int row = i >> 2, q = i & 3;
            float4 v = Sg[i];
            St[(4 * q + 0) * 260 + row] = v.x;
            St[(4 * q + 1) * 260 + row] = v.y;
            St[(4 * q + 2) * 260 + row] = v.z;
            St[(4 * q + 3) * 260 + row] = v.w;
        }
        Gl[t] = G[h * 256 + t];
    }
    __syncthreads();

    // R[r][l] = 2 * sum_k S[n0+r][k] * G_h[k][l]; thread t -> r=t>>2, l4=(t&3)*4
    {
        int r = t >> 2, l4 = (t & 3) * 4;
        const float4* mp = (const float4*)(S + (size_t)b * 4096 + (size_t)(n0 + r) * 16);
        float4 s0 = mp[0], s1 = mp[1], s2 = mp[2], s3 = mp[3];
        float sr[16] = { s0.x,s0.y,s0.z,s0.w, s1.x,s1.y,s1.z,s1.w,
                         s2.x,s2.y,s2.z,s2.w, s3.x,s3.y,s3.z,s3.w };
        float a0 = 0.f, a1 = 0.f, a2 = 0.f, a3 = 0.f;
        #pragma unroll
        for (int k = 0; k < 16; ++k) {
            float4 g = *(const float4*)(Gl + k * 16 + l4);
            a0 += sr[k] * g.x; a1 += sr[k] * g.y;
            a2 += sr[k] * g.z; a3 += sr[k] * g.w;
        }
        *(float4*)(Rl + r * 20 + l4) = make_float4(2.f*a0, 2.f*a1, 2.f*a2, 2.f*a3);
    }
    __syncthreads();

    // main: cg = t&63 -> columns 4cg..4cg+3; wave rs = t>>6 -> rows rs, rs+4, ...
    int cg = t & 63, rs = t >> 6;
    float sr[4][16];                       // S rows of my 4 columns
    #pragma unroll
    for (int k = 0; k < 16; ++k) {
        float4 v = *(const float4*)(St + k * 260 + 4 * cg);   // conflict-free b128
        sr[0][k] = v.x; sr[1][k] = v.y; sr[2][k] = v.z; sr[3][k] = v.w;
    }
    size_t obase = (size_t)bh * 65536 + (size_t)n0 * 256 + 4 * cg;
    for (int r = rs; r < 64; r += 4) {
        const float4* rp = (const float4*)(Rl + r * 20);      // wave-uniform bcast
        float4 r0 = rp[0], r1 = rp[1], r2 = rp[2], r3 = rp[3];
        float rv[16] = { r0.x,r0.y,r0.z,r0.w, r1.x,r1.y,r1.z,r1.w,
                         r2.x,r2.y,r2.z,r2.w, r3.x,r3.y,r3.z,r3.w };
        float x[4], e[4];
        #pragma unroll
        for (int j = 0; j < 4; ++j) {
            float a = 0.f;
            #pragma unroll
            for (int l = 0; l < 16; ++l) a += rv[l] * sr[j][l];
            x[j] = a;
            e[j] = __expf(a);
        }
        float ls = (e[0] + e[1]) + (e[2] + e[3]);
        #pragma unroll
        for (int off = 1; off < 64; off <<= 1) ls += __shfl_xor(ls, off);
        float lnL = __logf(ls);
        float rc = 1.f / ls;
        size_t ro = obase + (size_t)r * 256;
        *(float4*)(Q + ro)    = make_float4(e[0]*rc, e[1]*rc, e[2]*rc, e[3]*rc);
        *(float4*)(bias + ro) = make_float4(fmaxf(x[0]-lnL, LOG_EPS),
                                            fmaxf(x[1]-lnL, LOG_EPS),
                                            fmaxf(x[2]-lnL, LOG_EPS),
                                            fmaxf(x[3]-lnL, LOG_EPS));
    }
}

// ---------------------------------------------------------------------------
extern "C" void kernel_launch(void* const* d_in, const int* in_sizes, int n_in,
                              void* d_out, int out_size, void* d_ws, size_t ws_size,
                              hipStream_t stream) {
    const float* desc     = (const float*)d_in[0];
    const float* nv       = (const float*)d_in[1];
    const float* W_fusion = (const float*)d_in[2];
    const float* b_fusion = (const float*)d_in[3];
    const float* W_slot   = (const float*)d_in[4];
    const float* b_slot   = (const float*)d_in[5];
    const float* G_param  = (const float*)d_in[6];

    float* out = (float*)d_out;
    float* out_bias = out;
    float* out_Q    = out + 16777216;
    float* out_reg  = out + 33554432;

    float* ws    = (float*)d_ws;
    float* W_eff = ws;           // 8192
    float* b_eff = ws + 8192;    // 16
    float* G_out = ws + 8208;    // 2048
    float* S     = ws + 10256;   // 131072

    kA<<<32, 256, 0, stream>>>(W_fusion, b_fusion, W_slot, b_slot, W_eff, b_eff);
    kB<<<2049, 256, 0, stream>>>(desc, nv, W_eff, b_eff, G_param, S, G_out, out_reg);
    kC<<<1056, 256, 0, stream>>>(S, G_out, out_bias, out_Q, out_reg);
}